// Round 11
// baseline (260.298 us; speedup 1.0000x reference)
//
#include <hip/hip_runtime.h>
#include <cstdint>
#include <cstddef>

#define NT 256
#define LOG2E 1.4426950408889634f

typedef float v2f __attribute__((ext_vector_type(2)));
typedef float v4f __attribute__((ext_vector_type(4)));

#if defined(__has_builtin)
#  if __has_builtin(__builtin_amdgcn_exp2f)
#    define EXP2F(x) __builtin_amdgcn_exp2f(x)
#  else
#    define EXP2F(x) exp2f(x)
#  endif
#else
#  define EXP2F(x) exp2f(x)
#endif

// ---------------- shared-memory layout (float offsets) ----------------
enum {
  OFF_EEGB = 0,       // 8
  OFF_PSAW = 8,       // 16
  OFF_PSAB = 24,      // 8
  OFF_LOCW = 32,      // 24
  OFF_LOCB = 56,      // 8
  OFF_TGTW = 64,      // 8
  OFF_TGTB = 72,      // 8
  OFF_NG   = 80,      // 8
  OFF_NB   = 88,      // 8
  OFF_CINW = 96,      // 192 (q-rows pre-scaled by log2e)
  OFF_CINB = 288,     // 24
  OFF_COUTW= 312,     // 64
  OFF_COUTB= 376,     // 8
  OFF_SINW = 384,     // 192
  OFF_SINB = 576,     // 24
  OFF_SOUTW= 600,     // 64
  OFF_SOUTB= 664,     // 8
  OFF_OINW = 672,     // 192
  OFF_OINB = 864,     // 24
  OFF_OOUTW= 888,     // 64
  OFF_OOUTB= 952,     // 8
  OFF_FC1B = 960,     // 90 -> 1050
  OFF_PE30 = 1052,    // 8
  OFF_PE32 = 1060,    // 8 -> 1068
  OFF_Ebuf = 1068,    // 240
  OFF_Pbuf = 1308,    // 256
  OFF_Sbuf = 1564,    // 256
  OFF_Abuf = 1820,    // 256
  OFF_Lbuf = 2076,    // 256
  OFF_Tbuf = 2332,    // 256 (final q source; then final raw output for fc1)
  OFF_CAT  = 2588,    // 1008 -> 3596
  OFF_KV   = 3596,    // 5 sets: K at +set*288, V at +1440+set*288 -> 2880 -> 6476
  SM_TOTAL = 6476,    // 25904 B -> 6 blocks/CU, 24 waves
  OFF_KVV  = OFF_KV + 1440,
  // aliases into KV region (time-disjoint):
  OFF_EEGW = OFF_KV,            // 672 floats [o][84], dead before phase A1
  OFF_KF   = OFF_KV,            // final MHA K: 8h x 132 = 1056
  OFF_VF   = OFF_KV + 1056,     // final MHA V: 1056 (ends 5708)
  OFF_FCO  = OFF_KV + 2112,     // 90 (5708..5798, inside KV region, after KF/VF)
};

__device__ __forceinline__ float hsum4(v4f a) {
  v2f t = a.xy + a.zw;
  return t.x + t.y;
}

__device__ __forceinline__ float grp8_sum(float v) {
  v += __shfl_xor(v, 1);
  v += __shfl_xor(v, 2);
  v += __shfl_xor(v, 4);
  return v;
}

__device__ __forceinline__ float dot8(const float* __restrict__ x,
                                      const float* __restrict__ w, float bias) {
  v4f xa = *(const v4f*)x, xb = *(const v4f*)(x + 4);
  return bias + hsum4(xa * *(const v4f*)w + xb * *(const v4f*)(w + 4));
}

// single-row attention (no max pass: softmax shift-invariant, scores bounded)
// + out-proj via 8 intra-group shuffles + LayerNorm via shuffle reductions.
template<int LK>
__device__ __forceinline__ float attn_nv(float q, int h,
                                         const float* Kp, const float* Vp,
                                         const float* sm, int woutO, int boutO,
                                         float gg, float bb) {
  v4f l4 = {0.f,0.f,0.f,0.f}, A4 = {0.f,0.f,0.f,0.f};
  #pragma unroll
  for (int t = 0; t < (LK >> 2); t++) {
    v4f kk = *(const v4f*)(Kp + 4 * t);
    v4f vv = *(const v4f*)(Vp + 4 * t);
    v4f sc = kk * q;
    v4f ee = { EXP2F(sc.x), EXP2F(sc.y), EXP2F(sc.z), EXP2F(sc.w) };
    l4 += ee; A4 += ee * vv;
  }
  if constexpr ((LK & 3) != 0) {  // tail == 2 in all shapes used
    v2f kk = *(const v2f*)(Kp + (LK & ~3));
    v2f vv = *(const v2f*)(Vp + (LK & ~3));
    v2f sc = kk * q;
    v2f ee = { EXP2F(sc.x), EXP2F(sc.y) };
    l4.xy = l4.xy + ee; A4.xy = A4.xy + ee * vv;
  }
  float ov = hsum4(A4) * __builtin_amdgcn_rcpf(hsum4(l4));
  // out-projection: ov for all 8 heads lives in this 8-lane group
  int lb = (threadIdx.x & 63) & ~7;
  v4f woa = *(const v4f*)(sm + woutO + h * 8);
  v4f wob = *(const v4f*)(sm + woutO + h * 8 + 4);
  float a = sm[boutO + h];
  a = fmaf(__shfl(ov, lb + 0), woa.x, a);
  a = fmaf(__shfl(ov, lb + 1), woa.y, a);
  a = fmaf(__shfl(ov, lb + 2), woa.z, a);
  a = fmaf(__shfl(ov, lb + 3), woa.w, a);
  a = fmaf(__shfl(ov, lb + 4), wob.x, a);
  a = fmaf(__shfl(ov, lb + 5), wob.y, a);
  a = fmaf(__shfl(ov, lb + 6), wob.z, a);
  a = fmaf(__shfl(ov, lb + 7), wob.w, a);
  float mu = grp8_sum(a) * 0.125f;
  float dd = a - mu;
  float var = grp8_sum(dd * dd) * 0.125f;
  return fmaf(dd * rsqrtf(var + 1e-5f), gg, bb);
}

__global__ __launch_bounds__(NT, 6) void cmt_kernel(
    const float* __restrict__ eeg, const float* __restrict__ pupil,
    const float* __restrict__ speech, const float* __restrict__ action,
    const float* __restrict__ location, const float* __restrict__ tgt,
    const float* __restrict__ eeg_w, const float* __restrict__ eeg_b,
    const float* __restrict__ psa_w, const float* __restrict__ psa_b,
    const float* __restrict__ loc_w, const float* __restrict__ loc_b,
    const float* __restrict__ tgt_w, const float* __restrict__ tgt_b,
    const float* __restrict__ ng, const float* __restrict__ nb,
    const float* __restrict__ cin_w, const float* __restrict__ cin_b,
    const float* __restrict__ cout_w, const float* __restrict__ cout_b,
    const float* __restrict__ sin_w, const float* __restrict__ sin_b,
    const float* __restrict__ sout_w, const float* __restrict__ sout_b,
    const float* __restrict__ oin_w, const float* __restrict__ oin_b,
    const float* __restrict__ oout_w, const float* __restrict__ oout_b,
    const float* __restrict__ fc1_w, const float* __restrict__ fc1_b,
    float* __restrict__ out)
{
  __shared__ __align__(16) float sm[SM_TOTAL];
  const int tid = threadIdx.x;
  const int b = blockIdx.x;

#define CP(off, p, n) for (int i = tid; i < (n); i += NT) sm[(off)+i] = (p)[i]
#define CPQ(off, p, n, nq) for (int i = tid; i < (n); i += NT) sm[(off)+i] = (p)[i] * ((i < (nq)) ? LOG2E : 1.0f)

  // ---------- phase 0: stage weights ----------
  for (int i = tid; i < 640; i += NT) sm[OFF_EEGW + (i / 80) * 84 + (i % 80)] = eeg_w[i];
  CP(OFF_EEGB, eeg_b, 8);
  CP(OFF_PSAW, psa_w, 16);   CP(OFF_PSAB, psa_b, 8);
  CP(OFF_LOCW, loc_w, 24);   CP(OFF_LOCB, loc_b, 8);
  CP(OFF_TGTW, tgt_w, 8);    CP(OFF_TGTB, tgt_b, 8);
  CP(OFF_NG, ng, 8);         CP(OFF_NB, nb, 8);
  CPQ(OFF_CINW, cin_w, 192, 64);  CPQ(OFF_CINB, cin_b, 24, 8);
  CP(OFF_COUTW, cout_w, 64); CP(OFF_COUTB, cout_b, 8);
  CPQ(OFF_SINW, sin_w, 192, 64);  CPQ(OFF_SINB, sin_b, 24, 8);
  CP(OFF_SOUTW, sout_w, 64); CP(OFF_SOUTB, sout_b, 8);
  CPQ(OFF_OINW, oin_w, 192, 64);  CPQ(OFF_OINB, oin_b, 24, 8);
  CP(OFF_OOUTW, oout_w, 64); CP(OFF_OOUTB, oout_b, 8);
  CP(OFF_FC1B, fc1_b, 90);
  if (tid < 16) {
    const float divs[4] = {1.f, 0.1f, 0.01f, 0.001f};
    float pos = (tid < 8) ? 30.f : 32.f;
    int e = tid & 7;
    float x = pos * divs[e >> 1];
    float v = (e & 1) ? cosf(x) : sinf(x);
    sm[((tid < 8) ? OFF_PE30 : OFF_PE32) + e] = v;
  }
  __syncthreads();

  // ---------- phase 1: convs + positional encoding ----------
  if (tid < 240) {  // eeg conv2d -> e[30][8]
    int w = tid >> 3, o = tid & 7;
    const float* ep = eeg + (size_t)b * 4720 + 4 * w;
    const float* wr = sm + OFF_EEGW + o * 84;
    v4f acc4 = {0.f, 0.f, 0.f, 0.f};
    #pragma unroll
    for (int t = 0; t < 20; t++) {
      int ik0 = 2 * t, ik1 = 2 * t + 1;
      float2 x0 = *(const float2*)(ep + (ik0 / 20) * 2360 + (ik0 % 20) * 118);
      float2 x1 = *(const float2*)(ep + (ik1 / 20) * 2360 + (ik1 % 20) * 118);
      v4f xv = {x0.x, x0.y, x1.x, x1.y};
      acc4 += xv * *(const v4f*)(wr + 4 * t);
    }
    sm[OFF_Ebuf + w * 8 + o] = hsum4(acc4) + sm[OFF_EEGB + o] + sm[OFF_PE30 + o];
  }
  {  // conv1d k=1 pad=1 -> length-32 sequences, + pe32
    int t = tid >> 3, o = tid & 7;
    bool inb = (t >= 1 && t <= 30);
    int ti = t - 1;
    float pe = sm[OFF_PE32 + o];
    float w0 = sm[OFF_PSAW + 2 * o], w1 = sm[OFF_PSAW + 2 * o + 1];
    float pb = sm[OFF_PSAB + o];
    float vp = pb, vs = pb, va = pb;
    float vl = sm[OFF_LOCB + o], vt = sm[OFF_TGTB + o];
    if (inb) {
      const float* pp = pupil    + (size_t)b * 60 + ti;
      const float* sp = speech   + (size_t)b * 60 + ti;
      const float* ap = action   + (size_t)b * 60 + ti;
      const float* lp = location + (size_t)b * 90 + ti;
      vp = fmaf(pp[0], w0, fmaf(pp[30], w1, vp));
      vs = fmaf(sp[0], w0, fmaf(sp[30], w1, vs));
      va = fmaf(ap[0], w0, fmaf(ap[30], w1, va));
      vl = fmaf(lp[0],  sm[OFF_LOCW + 3 * o],     vl);
      vl = fmaf(lp[30], sm[OFF_LOCW + 3 * o + 1], vl);
      vl = fmaf(lp[60], sm[OFF_LOCW + 3 * o + 2], vl);
      vt = fmaf(tgt[(size_t)b * 30 + ti], sm[OFF_TGTW + o], vt);
    }
    sm[OFF_Pbuf + tid] = vp + pe;
    sm[OFF_Sbuf + tid] = vs + pe;
    sm[OFF_Abuf + tid] = va + pe;
    sm[OFF_Lbuf + tid] = vl + pe;
    sm[OFF_Tbuf + tid] = vt + pe;
  }
  __syncthreads();

  const int qi = tid >> 3, h = tid & 7;

  // ---------- phase A1: 5 cross K/V sets (0=e,1=p,2=s,3=a,4=l), weights hoisted ----------
  {
    const int r = qi;  // 0..31
    v4f cka = *(const v4f*)(sm + OFF_CINW + 64 + h * 8), ckb = *(const v4f*)(sm + OFF_CINW + 68 + h * 8);
    v4f cva = *(const v4f*)(sm + OFF_CINW + 128 + h * 8), cvb = *(const v4f*)(sm + OFF_CINW + 132 + h * 8);
    float cbk = sm[OFF_CINB + 8 + h], cbv = sm[OFF_CINB + 16 + h];
#define KV1(srcO, set) { \
    v4f xa = *(const v4f*)(sm + (srcO) + r * 8); \
    v4f xb = *(const v4f*)(sm + (srcO) + r * 8 + 4); \
    sm[OFF_KV  + (set) * 288 + h * 36 + r] = cbk + hsum4(xa * cka + xb * ckb); \
    sm[OFF_KVV + (set) * 288 + h * 36 + r] = cbv + hsum4(xa * cva + xb * cvb); }
    if (r < 30) KV1(OFF_Ebuf, 0);
    KV1(OFF_Pbuf, 1);
    KV1(OFF_Sbuf, 2);
    KV1(OFF_Abuf, 3);
    KV1(OFF_Lbuf, 4);
#undef KV1
  }
  __syncthreads();

  // ---------- phase B1: all 15 cross attns, straight-line, barrier-free ----------
#define KSET(s) (sm + OFF_KV  + (s) * 288 + h * 36)
#define VSET(s) (sm + OFF_KVV + (s) * 288 + h * 36)
  {
    const float gg = sm[OFF_NG + h], bb = sm[OFF_NB + h];
    float carry;  // nrm(cross(s,l)) handed s-target -> a-target (same thread)
    // --- target e (rows 0..29): 4 cross ---
    if (qi < 30) {
      float qc = dot8(sm + OFF_Ebuf + qi * 8, sm + OFF_CINW + h * 8, sm[OFF_CINB + h]);
      float cat = attn_nv<32>(qc, h, KSET(1), VSET(1), sm, OFF_COUTW, OFF_COUTB, gg, bb)   // e,p
                + attn_nv<32>(qc, h, KSET(3), VSET(3), sm, OFF_COUTW, OFF_COUTB, gg, bb)   // e,a
                + attn_nv<32>(qc, h, KSET(4), VSET(4), sm, OFF_COUTW, OFF_COUTB, gg, bb)   // e,l
                + attn_nv<32>(qc, h, KSET(2), VSET(2), sm, OFF_COUTW, OFF_COUTB, gg, bb);  // e,s
      sm[OFF_CAT + qi * 8 + h] = cat;
    }
    // --- target p (rows 30..61): 4 cross ---
    {
      float qc = dot8(sm + OFF_Pbuf + qi * 8, sm + OFF_CINW + h * 8, sm[OFF_CINB + h]);
      float cat = attn_nv<30>(qc, h, KSET(0), VSET(0), sm, OFF_COUTW, OFF_COUTB, gg, bb)   // p,e
                + attn_nv<32>(qc, h, KSET(3), VSET(3), sm, OFF_COUTW, OFF_COUTB, gg, bb)   // p,a
                + attn_nv<32>(qc, h, KSET(4), VSET(4), sm, OFF_COUTW, OFF_COUTB, gg, bb)   // p,l
                + attn_nv<32>(qc, h, KSET(2), VSET(2), sm, OFF_COUTW, OFF_COUTB, gg, bb);  // p,s
      sm[OFF_CAT + (30 + qi) * 8 + h] = cat;
    }
    // --- target s (rows 94..125): 4 cross (incl carry) ---
    {
      float qc = dot8(sm + OFF_Sbuf + qi * 8, sm + OFF_CINW + h * 8, sm[OFF_CINB + h]);
      float cat = attn_nv<30>(qc, h, KSET(0), VSET(0), sm, OFF_COUTW, OFF_COUTB, gg, bb)   // s,e
                + attn_nv<32>(qc, h, KSET(1), VSET(1), sm, OFF_COUTW, OFF_COUTB, gg, bb)   // s,p
                + attn_nv<32>(qc, h, KSET(3), VSET(3), sm, OFF_COUTW, OFF_COUTB, gg, bb);  // s,a
      carry     = attn_nv<32>(qc, h, KSET(4), VSET(4), sm, OFF_COUTW, OFF_COUTB, gg, bb);  // s,l
      sm[OFF_CAT + (94 + qi) * 8 + h] = cat + carry;
    }
    // --- target a (rows 62..93): 3 cross + carry (original aliasing bug) ---
    {
      float qc = dot8(sm + OFF_Abuf + qi * 8, sm + OFF_CINW + h * 8, sm[OFF_CINB + h]);
      float cat = attn_nv<30>(qc, h, KSET(0), VSET(0), sm, OFF_COUTW, OFF_COUTB, gg, bb)   // a,e
                + attn_nv<32>(qc, h, KSET(1), VSET(1), sm, OFF_COUTW, OFF_COUTB, gg, bb)   // a,p
                + attn_nv<32>(qc, h, KSET(2), VSET(2), sm, OFF_COUTW, OFF_COUTB, gg, bb)   // a,s
                + carry;
      sm[OFF_CAT + (62 + qi) * 8 + h] = cat;
    }
  }
  __syncthreads();

  // ---------- phase A2: 3 self K/V sets (0=e,1=p,2=a) into same slots ----------
  {
    const int r = qi;
    v4f ska = *(const v4f*)(sm + OFF_SINW + 64 + h * 8), skb = *(const v4f*)(sm + OFF_SINW + 68 + h * 8);
    v4f sva = *(const v4f*)(sm + OFF_SINW + 128 + h * 8), svb = *(const v4f*)(sm + OFF_SINW + 132 + h * 8);
    float sbk = sm[OFF_SINB + 8 + h], sbv = sm[OFF_SINB + 16 + h];
#define KV1(srcO, set) { \
    v4f xa = *(const v4f*)(sm + (srcO) + r * 8); \
    v4f xb = *(const v4f*)(sm + (srcO) + r * 8 + 4); \
    sm[OFF_KV  + (set) * 288 + h * 36 + r] = sbk + hsum4(xa * ska + xb * skb); \
    sm[OFF_KVV + (set) * 288 + h * 36 + r] = sbv + hsum4(xa * sva + xb * svb); }
    if (r < 30) KV1(OFF_Ebuf, 0);
    KV1(OFF_Pbuf, 1);
    KV1(OFF_Abuf, 2);
#undef KV1
  }
  __syncthreads();

  // ---------- phase B2: 3 self attns, accumulate into CAT ----------
  {
    const float gg = sm[OFF_NG + h], bb = sm[OFF_NB + h];
    if (qi < 30) {
      float qs = dot8(sm + OFF_Ebuf + qi * 8, sm + OFF_SINW + h * 8, sm[OFF_SINB + h]);
      sm[OFF_CAT + qi * 8 + h] += attn_nv<30>(qs, h, KSET(0), VSET(0), sm, OFF_SOUTW, OFF_SOUTB, gg, bb);
    }
    {
      float qs = dot8(sm + OFF_Pbuf + qi * 8, sm + OFF_SINW + h * 8, sm[OFF_SINB + h]);
      sm[OFF_CAT + (30 + qi) * 8 + h] += attn_nv<32>(qs, h, KSET(1), VSET(1), sm, OFF_SOUTW, OFF_SOUTB, gg, bb);
    }
    {
      float qs = dot8(sm + OFF_Abuf + qi * 8, sm + OFF_SINW + h * 8, sm[OFF_SINB + h]);
      sm[OFF_CAT + (62 + qi) * 8 + h] += attn_nv<32>(qs, h, KSET(2), VSET(2), sm, OFF_SOUTW, OFF_SOUTB, gg, bb);
    }
  }
#undef KSET
#undef VSET
  __syncthreads();

  // ---------- final MHA kv-proj of CAT (126 rows) into aliased KF/VF ----------
  {
    v4f fka = *(const v4f*)(sm + OFF_OINW + 64 + h * 8), fkb = *(const v4f*)(sm + OFF_OINW + 68 + h * 8);
    v4f fva = *(const v4f*)(sm + OFF_OINW + 128 + h * 8), fvb = *(const v4f*)(sm + OFF_OINW + 132 + h * 8);
    float fbk = sm[OFF_OINB + 8 + h], fbv = sm[OFF_OINB + 16 + h];
    for (int r = qi; r < 126; r += 32) {
      v4f xa = *(const v4f*)(sm + OFF_CAT + r * 8);
      v4f xb = *(const v4f*)(sm + OFF_CAT + r * 8 + 4);
      sm[OFF_KF + h * 132 + r] = fbk + hsum4(xa * fka + xb * fkb);
      sm[OFF_VF + h * 132 + r] = fbv + hsum4(xa * fva + xb * fvb);
    }
  }
  __syncthreads();

  // ---------- final attention (Lk=126, single row/thread) ----------
  {
    float qf = dot8(sm + OFF_Tbuf + qi * 8, sm + OFF_OINW + h * 8, sm[OFF_OINB + h]);
    const float* Kp = sm + OFF_KF + h * 132;
    const float* Vp = sm + OFF_VF + h * 132;
    v4f l4 = {0.f,0.f,0.f,0.f}, A4 = {0.f,0.f,0.f,0.f};
    #pragma unroll
    for (int t = 0; t < 31; t++) {
      v4f kk = *(const v4f*)(Kp + 4 * t);
      v4f vv = *(const v4f*)(Vp + 4 * t);
      v4f sc = kk * qf;
      v4f ee = { EXP2F(sc.x), EXP2F(sc.y), EXP2F(sc.z), EXP2F(sc.w) };
      l4 += ee; A4 += ee * vv;
    }
    {
      v2f kk = *(const v2f*)(Kp + 124);
      v2f vv = *(const v2f*)(Vp + 124);
      v2f sc = kk * qf;
      v2f ee = { EXP2F(sc.x), EXP2F(sc.y) };
      l4.xy = l4.xy + ee; A4.xy = A4.xy + ee * vv;
    }
    float ov = hsum4(A4) * __builtin_amdgcn_rcpf(hsum4(l4));
    int lb = (tid & 63) & ~7;
    v4f woa = *(const v4f*)(sm + OFF_OOUTW + h * 8);
    v4f wob = *(const v4f*)(sm + OFF_OOUTW + h * 8 + 4);
    float a = sm[OFF_OOUTB + h];
    a = fmaf(__shfl(ov, lb + 0), woa.x, a);
    a = fmaf(__shfl(ov, lb + 1), woa.y, a);
    a = fmaf(__shfl(ov, lb + 2), woa.z, a);
    a = fmaf(__shfl(ov, lb + 3), woa.w, a);
    a = fmaf(__shfl(ov, lb + 4), wob.x, a);
    a = fmaf(__shfl(ov, lb + 5), wob.y, a);
    a = fmaf(__shfl(ov, lb + 6), wob.z, a);
    a = fmaf(__shfl(ov, lb + 7), wob.w, a);
    __syncthreads();                  // KF/VF reads done before Tbuf rewrite & FCO alias
    sm[OFF_Tbuf + qi * 8 + h] = a;    // final raw output (32,8) for fc1
  }
  __syncthreads();

  // ---------- fc1 (2 threads per output) + channel softmax ----------
  if (tid < 180) {
    int j = tid >> 1, p = tid & 1;
    const v4f* w4 = (const v4f*)(fc1_w + j * 256);
    const v4f* o4 = (const v4f*)(sm + OFF_Tbuf);
    v4f acc4 = {0.f, 0.f, 0.f, 0.f};
    #pragma unroll 8
    for (int c = p; c < 64; c += 2) acc4 += o4[c] * w4[c];
    float acc = hsum4(acc4);
    acc += __shfl_xor(acc, 1);
    if (p == 0) sm[OFF_FCO + j] = acc + sm[OFF_FC1B + j];
  }
  __syncthreads();
  if (tid < 30) {
    float x0 = sm[OFF_FCO + 3 * tid], x1 = sm[OFF_FCO + 3 * tid + 1], x2 = sm[OFF_FCO + 3 * tid + 2];
    float m = fmaxf(x0, fmaxf(x1, x2));
    float e0 = __expf(x0 - m), e1 = __expf(x1 - m), e2 = __expf(x2 - m);
    float inv = __builtin_amdgcn_rcpf(e0 + e1 + e2);
    float* op = out + (size_t)b * 90;
    op[tid]      = e0 * inv;
    op[30 + tid] = e1 * inv;
    op[60 + tid] = e2 * inv;
  }
#undef CP
#undef CPQ
}

extern "C" void kernel_launch(void* const* d_in, const int* in_sizes, int n_in,
                              void* d_out, int out_size, void* d_ws, size_t ws_size,
                              hipStream_t stream) {
  (void)n_in; (void)out_size; (void)d_ws; (void)ws_size;
  int B = in_sizes[0] / 4720;  // eeg = (B,2,20,118)
  cmt_kernel<<<B, NT, 0, stream>>>(
      (const float*)d_in[0],  (const float*)d_in[1],  (const float*)d_in[2],
      (const float*)d_in[3],  (const float*)d_in[4],  (const float*)d_in[5],
      (const float*)d_in[6],  (const float*)d_in[7],  (const float*)d_in[8],
      (const float*)d_in[9],  (const float*)d_in[10], (const float*)d_in[11],
      (const float*)d_in[12], (const float*)d_in[13], (const float*)d_in[14],
      (const float*)d_in[15], (const float*)d_in[16], (const float*)d_in[17],
      (const float*)d_in[18], (const float*)d_in[19], (const float*)d_in[20],
      (const float*)d_in[21], (const float*)d_in[22], (const float*)d_in[23],
      (const float*)d_in[24], (const float*)d_in[25], (const float*)d_in[26],
      (const float*)d_in[27], (const float*)d_in[28], (const float*)d_in[29],
      (float*)d_out);
}

// Round 12
// 252.696 us; speedup vs baseline: 1.0301x; 1.0301x over previous
//
#include <hip/hip_runtime.h>
#include <cstdint>
#include <cstddef>

#define NT 256
#define LOG2E 1.4426950408889634f

typedef float v2f __attribute__((ext_vector_type(2)));
typedef float v4f __attribute__((ext_vector_type(4)));

#if defined(__has_builtin)
#  if __has_builtin(__builtin_amdgcn_exp2f)
#    define EXP2F(x) __builtin_amdgcn_exp2f(x)
#  else
#    define EXP2F(x) exp2f(x)
#  endif
#else
#  define EXP2F(x) exp2f(x)
#endif

// ---------------- shared-memory layout (float offsets) ----------------
enum {
  OFF_EEGB = 0,       // 8
  OFF_PSAW = 8,       // 16
  OFF_PSAB = 24,      // 8
  OFF_LOCW = 32,      // 24
  OFF_LOCB = 56,      // 8
  OFF_TGTW = 64,      // 8
  OFF_TGTB = 72,      // 8
  OFF_NG   = 80,      // 8
  OFF_NB   = 88,      // 8
  OFF_CINW = 96,      // 192 (q-rows pre-scaled by log2e)
  OFF_CINB = 288,     // 24
  OFF_COUTW= 312,     // 64
  OFF_COUTB= 376,     // 8
  OFF_SINW = 384,     // 192
  OFF_SINB = 576,     // 24
  OFF_SOUTW= 600,     // 64
  OFF_SOUTB= 664,     // 8
  OFF_OINW = 672,     // 192
  OFF_OINB = 864,     // 24
  OFF_OOUTW= 888,     // 64
  OFF_OOUTB= 952,     // 8
  OFF_FC1B = 960,     // 90 -> 1050
  OFF_PE30 = 1052,    // 8
  OFF_PE32 = 1060,    // 8 -> 1068
  OFF_Ebuf = 1068,    // 240
  OFF_Pbuf = 1308,    // 256
  OFF_Sbuf = 1564,    // 256
  OFF_Abuf = 1820,    // 256
  OFF_Lbuf = 2076,    // 256
  OFF_Tbuf = 2332,    // 256 (final q source; then final raw output for fc1)
  OFF_CAT  = 2588,    // 1008 -> 3596
  OFF_QP   = 3596,    // 32 groups x 20 (row1 @+0, row2 @+12) -> 4236
  OFF_K8   = 4236,    // 8 sets x 8h x 36 = 2304 -> 6540
  OFF_V8   = 6540,    // 2304 -> 8844
  OFF_FCO  = 8844,    // 90 -> 8934
  SM_TOTAL = 8936,    // 35744 B -> 4 blocks/CU
  // aliases into K8/V8 region (time-disjoint):
  OFF_EEGW = OFF_K8,            // 672 floats [o][84], dead before phase A
  OFF_KF   = OFF_K8,            // final MHA K: 8h x 132 = 1056
  OFF_VF   = OFF_K8 + 1056,     // final MHA V: 1056
};
// KV set ids: 0=e,1=p,2=s,3=a,4=l (cross-proj), 5=e,6=p,7=a (self-proj)

__device__ __forceinline__ float hsum4(v4f a) {
  v2f t = a.xy + a.zw;
  return t.x + t.y;
}

__device__ __forceinline__ float dot8(const float* __restrict__ x,
                                      const float* __restrict__ w, float bias) {
  v4f xa = *(const v4f*)x, xb = *(const v4f*)(x + 4);
  return bias + hsum4(xa * *(const v4f*)w + xb * *(const v4f*)(w + 4));
}

// 2-q-row softmax core: K/V read ONCE for both rows (no max pass: shift-invariant, bounded)
template<int LK>
__device__ __forceinline__ void attn2_core(float q1, float q2,
                                           const float* Kp, const float* Vp,
                                           float& ov1, float& ov2) {
  v4f la = {0.f,0.f,0.f,0.f}, Aa = la, lb = la, Ab = la;
  #pragma unroll
  for (int t = 0; t < (LK >> 2); t++) {
    v4f kk = *(const v4f*)(Kp + 4 * t);
    v4f vv = *(const v4f*)(Vp + 4 * t);
    v4f s1 = kk * q1, s2 = kk * q2;
    v4f e1 = { EXP2F(s1.x), EXP2F(s1.y), EXP2F(s1.z), EXP2F(s1.w) };
    v4f e2 = { EXP2F(s2.x), EXP2F(s2.y), EXP2F(s2.z), EXP2F(s2.w) };
    la += e1; Aa += e1 * vv;
    lb += e2; Ab += e2 * vv;
  }
  if constexpr ((LK & 3) != 0) {  // tail == 2 in all shapes used
    v2f kk = *(const v2f*)(Kp + (LK & ~3));
    v2f vv = *(const v2f*)(Vp + (LK & ~3));
    v2f s1 = kk * q1, s2 = kk * q2;
    v2f e1 = { EXP2F(s1.x), EXP2F(s1.y) };
    v2f e2 = { EXP2F(s2.x), EXP2F(s2.y) };
    la.xy = la.xy + e1; Aa.xy = Aa.xy + e1 * vv;
    lb.xy = lb.xy + e2; Ab.xy = Ab.xy + e2 * vv;
  }
  ov1 = hsum4(Aa) * __builtin_amdgcn_rcpf(hsum4(la));
  ov2 = hsum4(Ab) * __builtin_amdgcn_rcpf(hsum4(lb));
}

// 2-row attention + out-proj + LayerNorm, ZERO bpermutes:
// ov exchange (2w+4r b128), register dot, a exchange (2w+4r), moments in registers.
template<int LK>
__device__ __forceinline__ void attn2_nv(float q1, float q2,
                                         const float* Kp, const float* Vp,
                                         float* qslot, int h,
                                         v4f woa, v4f wob, float bo,
                                         float gg, float bb,
                                         float& nv1, float& nv2) {
  float ov1, ov2;
  attn2_core<LK>(q1, q2, Kp, Vp, ov1, ov2);
  // intra-8-lane-group exchange (same wave lockstep -> program order, no barrier)
  qslot[h] = ov1; qslot[12 + h] = ov2;
  v4f c0 = *(const v4f*)qslot,        c1 = *(const v4f*)(qslot + 4);
  v4f d0 = *(const v4f*)(qslot + 12), d1 = *(const v4f*)(qslot + 16);
  float a1 = bo + hsum4(c0 * woa + c1 * wob);
  float a2 = bo + hsum4(d0 * woa + d1 * wob);
  qslot[h] = a1; qslot[12 + h] = a2;
  c0 = *(const v4f*)qslot;        c1 = *(const v4f*)(qslot + 4);
  d0 = *(const v4f*)(qslot + 12); d1 = *(const v4f*)(qslot + 16);
  float mu1 = hsum4(c0 + c1) * 0.125f;
  float mu2 = hsum4(d0 + d1) * 0.125f;
  v4f e0 = c0 - mu1, e1 = c1 - mu1;
  v4f f0 = d0 - mu2, f1 = d1 - mu2;
  float var1 = hsum4(e0 * e0 + e1 * e1) * 0.125f;
  float var2 = hsum4(f0 * f0 + f1 * f1) * 0.125f;
  nv1 = fmaf((a1 - mu1) * rsqrtf(var1 + 1e-5f), gg, bb);
  nv2 = fmaf((a2 - mu2) * rsqrtf(var2 + 1e-5f), gg, bb);
}

__global__ __launch_bounds__(NT, 4) void cmt_kernel(
    const float* __restrict__ eeg, const float* __restrict__ pupil,
    const float* __restrict__ speech, const float* __restrict__ action,
    const float* __restrict__ location, const float* __restrict__ tgt,
    const float* __restrict__ eeg_w, const float* __restrict__ eeg_b,
    const float* __restrict__ psa_w, const float* __restrict__ psa_b,
    const float* __restrict__ loc_w, const float* __restrict__ loc_b,
    const float* __restrict__ tgt_w, const float* __restrict__ tgt_b,
    const float* __restrict__ ng, const float* __restrict__ nb,
    const float* __restrict__ cin_w, const float* __restrict__ cin_b,
    const float* __restrict__ cout_w, const float* __restrict__ cout_b,
    const float* __restrict__ sin_w, const float* __restrict__ sin_b,
    const float* __restrict__ sout_w, const float* __restrict__ sout_b,
    const float* __restrict__ oin_w, const float* __restrict__ oin_b,
    const float* __restrict__ oout_w, const float* __restrict__ oout_b,
    const float* __restrict__ fc1_w, const float* __restrict__ fc1_b,
    float* __restrict__ out)
{
  __shared__ __align__(16) float sm[SM_TOTAL];
  const int tid = threadIdx.x;
  const int b = blockIdx.x;

#define CP(off, p, n) for (int i = tid; i < (n); i += NT) sm[(off)+i] = (p)[i]
#define CPQ(off, p, n, nq) for (int i = tid; i < (n); i += NT) sm[(off)+i] = (p)[i] * ((i < (nq)) ? LOG2E : 1.0f)

  // ---------- phase 0: stage weights ----------
  for (int i = tid; i < 640; i += NT) sm[OFF_EEGW + (i / 80) * 84 + (i % 80)] = eeg_w[i];
  CP(OFF_EEGB, eeg_b, 8);
  CP(OFF_PSAW, psa_w, 16);   CP(OFF_PSAB, psa_b, 8);
  CP(OFF_LOCW, loc_w, 24);   CP(OFF_LOCB, loc_b, 8);
  CP(OFF_TGTW, tgt_w, 8);    CP(OFF_TGTB, tgt_b, 8);
  CP(OFF_NG, ng, 8);         CP(OFF_NB, nb, 8);
  CPQ(OFF_CINW, cin_w, 192, 64);  CPQ(OFF_CINB, cin_b, 24, 8);
  CP(OFF_COUTW, cout_w, 64); CP(OFF_COUTB, cout_b, 8);
  CPQ(OFF_SINW, sin_w, 192, 64);  CPQ(OFF_SINB, sin_b, 24, 8);
  CP(OFF_SOUTW, sout_w, 64); CP(OFF_SOUTB, sout_b, 8);
  CPQ(OFF_OINW, oin_w, 192, 64);  CPQ(OFF_OINB, oin_b, 24, 8);
  CP(OFF_OOUTW, oout_w, 64); CP(OFF_OOUTB, oout_b, 8);
  CP(OFF_FC1B, fc1_b, 90);
  if (tid < 16) {
    const float divs[4] = {1.f, 0.1f, 0.01f, 0.001f};
    float pos = (tid < 8) ? 30.f : 32.f;
    int e = tid & 7;
    float x = pos * divs[e >> 1];
    float v = (e & 1) ? cosf(x) : sinf(x);
    sm[((tid < 8) ? OFF_PE30 : OFF_PE32) + e] = v;
  }
  __syncthreads();

  // ---------- phase 1: convs + positional encoding ----------
  if (tid < 240) {  // eeg conv2d -> e[30][8]
    int w = tid >> 3, o = tid & 7;
    const float* ep = eeg + (size_t)b * 4720 + 4 * w;
    const float* wr = sm + OFF_EEGW + o * 84;
    v4f acc4 = {0.f, 0.f, 0.f, 0.f};
    #pragma unroll
    for (int t = 0; t < 20; t++) {
      int ik0 = 2 * t, ik1 = 2 * t + 1;
      float2 x0 = *(const float2*)(ep + (ik0 / 20) * 2360 + (ik0 % 20) * 118);
      float2 x1 = *(const float2*)(ep + (ik1 / 20) * 2360 + (ik1 % 20) * 118);
      v4f xv = {x0.x, x0.y, x1.x, x1.y};
      acc4 += xv * *(const v4f*)(wr + 4 * t);
    }
    sm[OFF_Ebuf + w * 8 + o] = hsum4(acc4) + sm[OFF_EEGB + o] + sm[OFF_PE30 + o];
  }
  {  // conv1d k=1 pad=1 -> length-32 sequences, + pe32
    int t = tid >> 3, o = tid & 7;
    bool inb = (t >= 1 && t <= 30);
    int ti = t - 1;
    float pe = sm[OFF_PE32 + o];
    float w0 = sm[OFF_PSAW + 2 * o], w1 = sm[OFF_PSAW + 2 * o + 1];
    float pb = sm[OFF_PSAB + o];
    float vp = pb, vs = pb, va = pb;
    float vl = sm[OFF_LOCB + o], vt = sm[OFF_TGTB + o];
    if (inb) {
      const float* pp = pupil    + (size_t)b * 60 + ti;
      const float* sp = speech   + (size_t)b * 60 + ti;
      const float* ap = action   + (size_t)b * 60 + ti;
      const float* lp = location + (size_t)b * 90 + ti;
      vp = fmaf(pp[0], w0, fmaf(pp[30], w1, vp));
      vs = fmaf(sp[0], w0, fmaf(sp[30], w1, vs));
      va = fmaf(ap[0], w0, fmaf(ap[30], w1, va));
      vl = fmaf(lp[0],  sm[OFF_LOCW + 3 * o],     vl);
      vl = fmaf(lp[30], sm[OFF_LOCW + 3 * o + 1], vl);
      vl = fmaf(lp[60], sm[OFF_LOCW + 3 * o + 2], vl);
      vt = fmaf(tgt[(size_t)b * 30 + ti], sm[OFF_TGTW + o], vt);
    }
    sm[OFF_Pbuf + tid] = vp + pe;
    sm[OFF_Sbuf + tid] = vs + pe;
    sm[OFF_Abuf + tid] = va + pe;
    sm[OFF_Lbuf + tid] = vl + pe;
    sm[OFF_Tbuf + tid] = vt + pe;
  }
  __syncthreads();

  const int g = tid >> 3, h = tid & 7;
  float* qslot = sm + OFF_QP + g * 20;

  // ---------- phase A: ALL 8 K/V sets, weights hoisted (scoped) ----------
  {
    const int r = g;  // 0..31
    v4f cka = *(const v4f*)(sm + OFF_CINW + 64 + h * 8), ckb = *(const v4f*)(sm + OFF_CINW + 68 + h * 8);
    v4f cva = *(const v4f*)(sm + OFF_CINW + 128 + h * 8), cvb = *(const v4f*)(sm + OFF_CINW + 132 + h * 8);
    float cbk = sm[OFF_CINB + 8 + h], cbv = sm[OFF_CINB + 16 + h];
#define KV1(srcO, set, wka, wkb, wva, wvb, bk, bv) { \
    v4f xa = *(const v4f*)(sm + (srcO) + r * 8); \
    v4f xb = *(const v4f*)(sm + (srcO) + r * 8 + 4); \
    sm[OFF_K8 + (set) * 288 + h * 36 + r] = (bk) + hsum4(xa * (wka) + xb * (wkb)); \
    sm[OFF_V8 + (set) * 288 + h * 36 + r] = (bv) + hsum4(xa * (wva) + xb * (wvb)); }
    if (r < 30) KV1(OFF_Ebuf, 0, cka, ckb, cva, cvb, cbk, cbv);
    KV1(OFF_Pbuf, 1, cka, ckb, cva, cvb, cbk, cbv);
    KV1(OFF_Sbuf, 2, cka, ckb, cva, cvb, cbk, cbv);
    KV1(OFF_Abuf, 3, cka, ckb, cva, cvb, cbk, cbv);
    KV1(OFF_Lbuf, 4, cka, ckb, cva, cvb, cbk, cbv);
    v4f ska = *(const v4f*)(sm + OFF_SINW + 64 + h * 8), skb = *(const v4f*)(sm + OFF_SINW + 68 + h * 8);
    v4f sva = *(const v4f*)(sm + OFF_SINW + 128 + h * 8), svb = *(const v4f*)(sm + OFF_SINW + 132 + h * 8);
    float sbk = sm[OFF_SINB + 8 + h], sbv = sm[OFF_SINB + 16 + h];
    if (r < 30) KV1(OFF_Ebuf, 5, ska, skb, sva, svb, sbk, sbv);
    KV1(OFF_Pbuf, 6, ska, skb, sva, svb, sbk, sbv);
    KV1(OFF_Abuf, 7, ska, skb, sva, svb, sbk, sbv);
#undef KV1
  }
  __syncthreads();

  // ---------- phase B: 18 MHAs, 2 rows/thread, targets split across wave pairs ----------
#define KSET(s) (sm + OFF_K8 + (s) * 288 + h * 36)
#define VSET(s) (sm + OFF_V8 + (s) * 288 + h * 36)
  {
    const float gg = sm[OFF_NG + h], bb = sm[OFF_NB + h];
    float t1, t2;
    // cross out-proj weights hoisted (shared by all 15 cross attns)
    v4f woc_a = *(const v4f*)(sm + OFF_COUTW + h * 8), woc_b = *(const v4f*)(sm + OFF_COUTW + h * 8 + 4);
    float boc = sm[OFF_COUTB + h];
    if (g < 16) {
      // ---- target e: rows g and g+16 (clamped; duplicate discarded) ----
      {
        const int r2 = (g < 14) ? g + 16 : 13;
        float qc1 = dot8(sm + OFF_Ebuf + g * 8,  sm + OFF_CINW + h * 8, sm[OFF_CINB + h]);
        float qc2 = dot8(sm + OFF_Ebuf + r2 * 8, sm + OFF_CINW + h * 8, sm[OFF_CINB + h]);
        float cat1, cat2;
        attn2_nv<32>(qc1, qc2, KSET(1), VSET(1), qslot, h, woc_a, woc_b, boc, gg, bb, cat1, cat2); // e,p
        attn2_nv<32>(qc1, qc2, KSET(3), VSET(3), qslot, h, woc_a, woc_b, boc, gg, bb, t1, t2);     // e,a
        cat1 += t1; cat2 += t2;
        attn2_nv<32>(qc1, qc2, KSET(4), VSET(4), qslot, h, woc_a, woc_b, boc, gg, bb, t1, t2);     // e,l
        cat1 += t1; cat2 += t2;
        attn2_nv<32>(qc1, qc2, KSET(2), VSET(2), qslot, h, woc_a, woc_b, boc, gg, bb, t1, t2);     // e,s
        cat1 += t1; cat2 += t2;
        {  // selfa(e)
          float qs1 = dot8(sm + OFF_Ebuf + g * 8,  sm + OFF_SINW + h * 8, sm[OFF_SINB + h]);
          float qs2 = dot8(sm + OFF_Ebuf + r2 * 8, sm + OFF_SINW + h * 8, sm[OFF_SINB + h]);
          v4f wsa = *(const v4f*)(sm + OFF_SOUTW + h * 8), wsb = *(const v4f*)(sm + OFF_SOUTW + h * 8 + 4);
          attn2_nv<30>(qs1, qs2, KSET(5), VSET(5), qslot, h, wsa, wsb, sm[OFF_SOUTB + h], gg, bb, t1, t2);
          cat1 += t1; cat2 += t2;
        }
        sm[OFF_CAT + g * 8 + h] = cat1;
        if (g < 14) sm[OFF_CAT + (g + 16) * 8 + h] = cat2;
      }
      // ---- target p: rows g and g+16 ----
      {
        float qc1 = dot8(sm + OFF_Pbuf + g * 8,        sm + OFF_CINW + h * 8, sm[OFF_CINB + h]);
        float qc2 = dot8(sm + OFF_Pbuf + (g + 16) * 8, sm + OFF_CINW + h * 8, sm[OFF_CINB + h]);
        float cat1, cat2;
        attn2_nv<30>(qc1, qc2, KSET(0), VSET(0), qslot, h, woc_a, woc_b, boc, gg, bb, cat1, cat2); // p,e
        attn2_nv<32>(qc1, qc2, KSET(3), VSET(3), qslot, h, woc_a, woc_b, boc, gg, bb, t1, t2);     // p,a
        cat1 += t1; cat2 += t2;
        attn2_nv<32>(qc1, qc2, KSET(4), VSET(4), qslot, h, woc_a, woc_b, boc, gg, bb, t1, t2);     // p,l
        cat1 += t1; cat2 += t2;
        attn2_nv<32>(qc1, qc2, KSET(2), VSET(2), qslot, h, woc_a, woc_b, boc, gg, bb, t1, t2);     // p,s
        cat1 += t1; cat2 += t2;
        {  // selfa(p)
          float qs1 = dot8(sm + OFF_Pbuf + g * 8,        sm + OFF_SINW + h * 8, sm[OFF_SINB + h]);
          float qs2 = dot8(sm + OFF_Pbuf + (g + 16) * 8, sm + OFF_SINW + h * 8, sm[OFF_SINB + h]);
          v4f wsa = *(const v4f*)(sm + OFF_SOUTW + h * 8), wsb = *(const v4f*)(sm + OFF_SOUTW + h * 8 + 4);
          attn2_nv<32>(qs1, qs2, KSET(6), VSET(6), qslot, h, wsa, wsb, sm[OFF_SOUTB + h], gg, bb, t1, t2);
          cat1 += t1; cat2 += t2;
        }
        sm[OFF_CAT + (30 + g) * 8 + h] = cat1;
        sm[OFF_CAT + (30 + g + 16) * 8 + h] = cat2;
      }
    } else {
      const int gq = g - 16;
      float car1, car2;
      // ---- target s: rows gq and gq+16 ----
      {
        float qc1 = dot8(sm + OFF_Sbuf + gq * 8,        sm + OFF_CINW + h * 8, sm[OFF_CINB + h]);
        float qc2 = dot8(sm + OFF_Sbuf + (gq + 16) * 8, sm + OFF_CINW + h * 8, sm[OFF_CINB + h]);
        float cat1, cat2;
        attn2_nv<30>(qc1, qc2, KSET(0), VSET(0), qslot, h, woc_a, woc_b, boc, gg, bb, cat1, cat2); // s,e
        attn2_nv<32>(qc1, qc2, KSET(1), VSET(1), qslot, h, woc_a, woc_b, boc, gg, bb, t1, t2);     // s,p
        cat1 += t1; cat2 += t2;
        attn2_nv<32>(qc1, qc2, KSET(3), VSET(3), qslot, h, woc_a, woc_b, boc, gg, bb, t1, t2);     // s,a
        cat1 += t1; cat2 += t2;
        attn2_nv<32>(qc1, qc2, KSET(4), VSET(4), qslot, h, woc_a, woc_b, boc, gg, bb, car1, car2); // s,l
        sm[OFF_CAT + (94 + gq) * 8 + h] = cat1 + car1;
        sm[OFF_CAT + (94 + gq + 16) * 8 + h] = cat2 + car2;
      }
      // ---- target a: rows gq and gq+16 (carry = nrm(cross(s,l)), original bug) ----
      {
        float qc1 = dot8(sm + OFF_Abuf + gq * 8,        sm + OFF_CINW + h * 8, sm[OFF_CINB + h]);
        float qc2 = dot8(sm + OFF_Abuf + (gq + 16) * 8, sm + OFF_CINW + h * 8, sm[OFF_CINB + h]);
        float cat1, cat2;
        attn2_nv<30>(qc1, qc2, KSET(0), VSET(0), qslot, h, woc_a, woc_b, boc, gg, bb, cat1, cat2); // a,e
        attn2_nv<32>(qc1, qc2, KSET(1), VSET(1), qslot, h, woc_a, woc_b, boc, gg, bb, t1, t2);     // a,p
        cat1 += t1 + car1; cat2 += t2 + car2;
        attn2_nv<32>(qc1, qc2, KSET(2), VSET(2), qslot, h, woc_a, woc_b, boc, gg, bb, t1, t2);     // a,s
        cat1 += t1; cat2 += t2;
        {  // selfa(a)
          float qs1 = dot8(sm + OFF_Abuf + gq * 8,        sm + OFF_SINW + h * 8, sm[OFF_SINB + h]);
          float qs2 = dot8(sm + OFF_Abuf + (gq + 16) * 8, sm + OFF_SINW + h * 8, sm[OFF_SINB + h]);
          v4f wsa = *(const v4f*)(sm + OFF_SOUTW + h * 8), wsb = *(const v4f*)(sm + OFF_SOUTW + h * 8 + 4);
          attn2_nv<32>(qs1, qs2, KSET(7), VSET(7), qslot, h, wsa, wsb, sm[OFF_SOUTB + h], gg, bb, t1, t2);
          cat1 += t1; cat2 += t2;
        }
        sm[OFF_CAT + (62 + gq) * 8 + h] = cat1;
        sm[OFF_CAT + (62 + gq + 16) * 8 + h] = cat2;
      }
    }
  }
#undef KSET
#undef VSET
  __syncthreads();

  // ---------- final MHA kv-proj of CAT (126 rows), weights hoisted (scoped) ----------
  {
    v4f fka = *(const v4f*)(sm + OFF_OINW + 64 + h * 8), fkb = *(const v4f*)(sm + OFF_OINW + 68 + h * 8);
    v4f fva = *(const v4f*)(sm + OFF_OINW + 128 + h * 8), fvb = *(const v4f*)(sm + OFF_OINW + 132 + h * 8);
    float fbk = sm[OFF_OINB + 8 + h], fbv = sm[OFF_OINB + 16 + h];
    for (int r = g; r < 126; r += 32) {
      v4f xa = *(const v4f*)(sm + OFF_CAT + r * 8);
      v4f xb = *(const v4f*)(sm + OFF_CAT + r * 8 + 4);
      sm[OFF_KF + h * 132 + r] = fbk + hsum4(xa * fka + xb * fkb);
      sm[OFF_VF + h * 132 + r] = fbv + hsum4(xa * fva + xb * fvb);
    }
  }
  __syncthreads();

  // ---------- final attention (Lk=126, 1 row/thread, exchange-based out-proj) ----------
  {
    float qf = dot8(sm + OFF_Tbuf + g * 8, sm + OFF_OINW + h * 8, sm[OFF_OINB + h]);
    const float* Kp = sm + OFF_KF + h * 132;
    const float* Vp = sm + OFF_VF + h * 132;
    v4f l4 = {0.f,0.f,0.f,0.f}, A4 = {0.f,0.f,0.f,0.f};
    #pragma unroll
    for (int t = 0; t < 31; t++) {
      v4f kk = *(const v4f*)(Kp + 4 * t);
      v4f vv = *(const v4f*)(Vp + 4 * t);
      v4f sc = kk * qf;
      v4f ee = { EXP2F(sc.x), EXP2F(sc.y), EXP2F(sc.z), EXP2F(sc.w) };
      l4 += ee; A4 += ee * vv;
    }
    {
      v2f kk = *(const v2f*)(Kp + 124);
      v2f vv = *(const v2f*)(Vp + 124);
      v2f sc = kk * qf;
      v2f ee = { EXP2F(sc.x), EXP2F(sc.y) };
      l4.xy = l4.xy + ee; A4.xy = A4.xy + ee * vv;
    }
    float ov = hsum4(A4) * __builtin_amdgcn_rcpf(hsum4(l4));
    qslot[h] = ov;
    v4f c0 = *(const v4f*)qslot, c1 = *(const v4f*)(qslot + 4);
    v4f woa = *(const v4f*)(sm + OFF_OOUTW + h * 8), wob = *(const v4f*)(sm + OFF_OOUTW + h * 8 + 4);
    float a = sm[OFF_OOUTB + h] + hsum4(c0 * woa + c1 * wob);
    sm[OFF_Tbuf + g * 8 + h] = a;  // wave-lockstep: qf read precedes this store
  }
  __syncthreads();

  // ---------- fc1 (2 threads per output) + channel softmax ----------
  if (tid < 180) {
    int j = tid >> 1, p = tid & 1;
    const v4f* w4 = (const v4f*)(fc1_w + j * 256);
    const v4f* o4 = (const v4f*)(sm + OFF_Tbuf);
    v4f acc4 = {0.f, 0.f, 0.f, 0.f};
    #pragma unroll 8
    for (int c = p; c < 64; c += 2) acc4 += o4[c] * w4[c];
    float acc = hsum4(acc4);
    acc += __shfl_xor(acc, 1);
    if (p == 0) sm[OFF_FCO + j] = acc + sm[OFF_FC1B + j];
  }
  __syncthreads();
  if (tid < 30) {
    float x0 = sm[OFF_FCO + 3 * tid], x1 = sm[OFF_FCO + 3 * tid + 1], x2 = sm[OFF_FCO + 3 * tid + 2];
    float m = fmaxf(x0, fmaxf(x1, x2));
    float e0 = __expf(x0 - m), e1 = __expf(x1 - m), e2 = __expf(x2 - m);
    float inv = __builtin_amdgcn_rcpf(e0 + e1 + e2);
    float* op = out + (size_t)b * 90;
    op[tid]      = e0 * inv;
    op[30 + tid] = e1 * inv;
    op[60 + tid] = e2 * inv;
  }
#undef CP
#undef CPQ
}

extern "C" void kernel_launch(void* const* d_in, const int* in_sizes, int n_in,
                              void* d_out, int out_size, void* d_ws, size_t ws_size,
                              hipStream_t stream) {
  (void)n_in; (void)out_size; (void)d_ws; (void)ws_size;
  int B = in_sizes[0] / 4720;  // eeg = (B,2,20,118)
  cmt_kernel<<<B, NT, 0, stream>>>(
      (const float*)d_in[0],  (const float*)d_in[1],  (const float*)d_in[2],
      (const float*)d_in[3],  (const float*)d_in[4],  (const float*)d_in[5],
      (const float*)d_in[6],  (const float*)d_in[7],  (const float*)d_in[8],
      (const float*)d_in[9],  (const float*)d_in[10], (const float*)d_in[11],
      (const float*)d_in[12], (const float*)d_in[13], (const float*)d_in[14],
      (const float*)d_in[15], (const float*)d_in[16], (const float*)d_in[17],
      (const float*)d_in[18], (const float*)d_in[19], (const float*)d_in[20],
      (const float*)d_in[21], (const float*)d_in[22], (const float*)d_in[23],
      (const float*)d_in[24], (const float*)d_in[25], (const float*)d_in[26],
      (const float*)d_in[27], (const float*)d_in[28], (const float*)d_in[29],
      (float*)d_out);
}